// Round 1
// baseline (190.878 us; speedup 1.0000x reference)
//
#include <hip/hip_runtime.h>
#include <hip/hip_bf16.h>

// CenterLoss: loss = ( sum_i clamp(||x_i - c_{label_i}||^2, 1e-12, 1e12)
//                      + B*(C-1)*1e-12 ) / B
// The full [B,C] distmat in the reference is masked down to one entry per row;
// all masked-out zeros become 1e-12 via the clamp -> constant term.

#define BATCH 8192
#define NUM_CLASSES 751
#define FEAT_DIM 2048

__global__ void center_loss_init(float* __restrict__ out) {
    // constant term: (B*(C-1)*1e-12)/B = (C-1)*1e-12 = 750e-12
    out[0] = 7.5e-10f;
}

__global__ __launch_bounds__(256) void center_loss_kernel(
        const float* __restrict__ x,
        const int* __restrict__ labels,
        const float* __restrict__ centers,
        float* __restrict__ out) {
    const int row = blockIdx.x;
    const int t = threadIdx.x;
    const int lab = labels[row];

    const float4* __restrict__ xr = (const float4*)(x + (size_t)row * FEAT_DIM);
    const float4* __restrict__ cr = (const float4*)(centers + (size_t)lab * FEAT_DIM);

    // FEAT_DIM/4 = 512 float4 per row; 256 threads -> 2 float4 each.
    float acc = 0.0f;
#pragma unroll
    for (int k = 0; k < 2; ++k) {
        const float4 xv = xr[t + k * 256];
        const float4 cv = cr[t + k * 256];
        const float d0 = xv.x - cv.x;
        const float d1 = xv.y - cv.y;
        const float d2 = xv.z - cv.z;
        const float d3 = xv.w - cv.w;
        acc += d0 * d0 + d1 * d1 + d2 * d2 + d3 * d3;
    }

    // wave(64) shuffle reduction
#pragma unroll
    for (int off = 32; off > 0; off >>= 1)
        acc += __shfl_down(acc, off, 64);

    __shared__ float ws[4];
    if ((t & 63) == 0) ws[t >> 6] = acc;
    __syncthreads();

    if (t == 0) {
        float s = ws[0] + ws[1] + ws[2] + ws[3];
        s = fminf(fmaxf(s, 1e-12f), 1e12f);
        atomicAdd(out, s * (1.0f / BATCH));
    }
}

extern "C" void kernel_launch(void* const* d_in, const int* in_sizes, int n_in,
                              void* d_out, int out_size, void* d_ws, size_t ws_size,
                              hipStream_t stream) {
    const float* x = (const float*)d_in[0];
    const int* labels = (const int*)d_in[1];
    const float* centers = (const float*)d_in[2];
    float* out = (float*)d_out;

    center_loss_init<<<1, 1, 0, stream>>>(out);
    center_loss_kernel<<<BATCH, 256, 0, stream>>>(x, labels, centers, out);
}

// Round 2
// 101.272 us; speedup vs baseline: 1.8848x; 1.8848x over previous
//
#include <hip/hip_runtime.h>
#include <hip/hip_bf16.h>

// CenterLoss: loss = ( sum_i clamp(||x_i - c_{label_i}||^2, 1e-12, 1e12)
//                      + B*(C-1)*1e-12 ) / B
// Round 1: 110us @ 533 GB/s -- serialized on 8192 same-address atomicAdds.
// Round 2: block-local partials -> d_ws, tiny tree-reduce kernel. No atomics.

#define BATCH 8192
#define NUM_CLASSES 751
#define FEAT_DIM 2048
#define NB 2048          // blocks in main kernel; 4 waves/block = 8192 rows

__global__ __launch_bounds__(256) void center_loss_main(
        const float* __restrict__ x,
        const int* __restrict__ labels,
        const float* __restrict__ centers,
        float* __restrict__ partial) {
    const int t = threadIdx.x;
    const int wave = t >> 6;
    const int lane = t & 63;
    const int row = blockIdx.x * 4 + wave;   // one wave per row, exact cover
    const int lab = labels[row];

    const float4* __restrict__ xr = (const float4*)(x + (size_t)row * FEAT_DIM);
    const float4* __restrict__ cr = (const float4*)(centers + (size_t)lab * FEAT_DIM);

    // 2048 floats/row = 512 float4; 64 lanes -> 8 float4 per lane.
    float acc = 0.0f;
#pragma unroll
    for (int k = 0; k < 8; ++k) {
        const float4 xv = xr[lane + k * 64];
        const float4 cv = cr[lane + k * 64];
        const float d0 = xv.x - cv.x;
        const float d1 = xv.y - cv.y;
        const float d2 = xv.z - cv.z;
        const float d3 = xv.w - cv.w;
        acc += d0 * d0 + d1 * d1 + d2 * d2 + d3 * d3;
    }

    // wave(64) shuffle reduction
#pragma unroll
    for (int off = 32; off > 0; off >>= 1)
        acc += __shfl_down(acc, off, 64);

    __shared__ float ws[4];
    if (lane == 0) {
        // clamp is per-row, so apply at wave granularity
        ws[wave] = fminf(fmaxf(acc, 1e-12f), 1e12f);
    }
    __syncthreads();

    if (t == 0)
        partial[blockIdx.x] = ws[0] + ws[1] + ws[2] + ws[3];
}

__global__ __launch_bounds__(256) void center_loss_reduce(
        const float* __restrict__ partial,
        float* __restrict__ out) {
    const int t = threadIdx.x;
    float s = 0.0f;
#pragma unroll
    for (int i = 0; i < NB / 256; ++i)
        s += partial[t + i * 256];

#pragma unroll
    for (int off = 32; off > 0; off >>= 1)
        s += __shfl_down(s, off, 64);

    __shared__ float ws[4];
    if ((t & 63) == 0) ws[t >> 6] = s;
    __syncthreads();

    if (t == 0) {
        // constant term: (C-1)*1e-12 per row -> (C-1)*1e-12 after /B
        out[0] = (ws[0] + ws[1] + ws[2] + ws[3]) * (1.0f / BATCH) + 7.5e-10f;
    }
}

extern "C" void kernel_launch(void* const* d_in, const int* in_sizes, int n_in,
                              void* d_out, int out_size, void* d_ws, size_t ws_size,
                              hipStream_t stream) {
    const float* x = (const float*)d_in[0];
    const int* labels = (const int*)d_in[1];
    const float* centers = (const float*)d_in[2];
    float* out = (float*)d_out;
    float* partial = (float*)d_ws;   // NB floats = 8 KB scratch

    center_loss_main<<<NB, 256, 0, stream>>>(x, labels, centers, partial);
    center_loss_reduce<<<1, 256, 0, stream>>>(partial, out);
}